// Round 10
// baseline (132.309 us; speedup 1.0000x reference)
//
#include <hip/hip_runtime.h>
#include <hip/hip_bf16.h>
#include <math.h>

// B=4, N=2048, C=320, H=5, D=64, INNER=320, BH=20
// logit = (q*0.125*log2e*e_i) . (k*e_j); softmax via exp2 (bounded, no max).
// e_bh = edge[(b+h)%4]  (batch-minor edge tiling vs batch-major heads)
//
// Fragment-major layouts (every main-loop load = lane-contiguous b128):
//  xb  tiles (mt2=m/16, kc=k/32): elem (qq*16+mm)*8+e  = x[m][k], qq=(k%32)>>3
//  wt  tiles (z, nt2=n/16, kc):   elem (qq*16+nn)*8+e  = W[k][n]
//  kS  [bh][j/16][d/32][slot]:    slot ((d>>3)&3)*16+(j&15), e=d&7
//  vS  [bh][d/16][j/64][kb][slot]: PV mfma32 A-frag order (see r3 notes)
//  ao  tiles like xb (A-operand of oproj)
//  qp  row-major [bh][n][64]
//
// r10 attn: 64 q-rows/block at 3 waves/SIMD. Q-frags live in LDS (re-read
// per unit), V single-buffered, K ping-pong prefetch forced by
// sched_barrier(0). LDS qbuf aliases the cross-wave partial buffer.

typedef short bf16x8 __attribute__((ext_vector_type(8)));
typedef float f32x4 __attribute__((ext_vector_type(4)));

static __device__ __forceinline__ ushort f2bf(float f) {
  union { float f; unsigned u; } v; v.f = f;
  unsigned r = (v.u + 0x7fffu + ((v.u >> 16) & 1u)) >> 16;
  return (ushort)r;
}
static __device__ __forceinline__ float fexp2(float x) {
#if __has_builtin(__builtin_amdgcn_exp2f)
  return __builtin_amdgcn_exp2f(x);
#else
  return exp2f(x);
#endif
}
static __device__ __forceinline__ f32x4 mfma32(bf16x8 a, bf16x8 b, f32x4 c) {
  return __builtin_amdgcn_mfma_f32_16x16x32_bf16(a, b, c, 0, 0, 0);
}

// ---------------------------------------------------------------------------
// Prep (fused): flat grid 3360. (verbatim r9)
// ---------------------------------------------------------------------------
__global__ __launch_bounds__(256) void prep_kernel(
    const float* __restrict__ x,
    const float* __restrict__ Wq, const float* __restrict__ Wk,
    const float* __restrict__ Wv, const float* __restrict__ Wo,
    ushort* __restrict__ xb, ushort* __restrict__ wt)
{
  const int w = blockIdx.x;
  if (w < 2560) {
    const int t = threadIdx.x;
    const int mt2 = w / 5;
    const int kc = (w % 5) * 2 + (t >> 7);
    const int f = (t & 127) * 4;
    const int qq = f >> 7, mm = (f >> 3) & 15, e0 = f & 7;
    float4 v = *reinterpret_cast<const float4*>(
        x + (size_t)(mt2 * 16 + mm) * 320 + kc * 32 + qq * 8 + e0);
    ushort4 o = { f2bf(v.x), f2bf(v.y), f2bf(v.z), f2bf(v.w) };
    *reinterpret_cast<ushort4*>(xb + (size_t)(mt2 * 10 + kc) * 512 + f) = o;
  } else {
    const int w2 = w - 2560;
    const int nt2 = w2 % 20, kc = (w2 / 20) % 10, z = w2 / 200;
    const float* W = z == 0 ? Wq : z == 1 ? Wk : z == 2 ? Wv : Wo;
    const int f = threadIdx.x * 2;
    const int qq = f >> 7, nn = (f >> 3) & 15, e0 = f & 7;
    const int k = kc * 32 + qq * 8 + e0, n = nt2 * 16 + nn;
    float v0 = W[(size_t)k * 320 + n];
    float v1 = W[(size_t)(k + 1) * 320 + n];
    ushort2 o = { f2bf(v0), f2bf(v1) };
    *reinterpret_cast<ushort2*>(
        wt + (size_t)z * 102400 + (size_t)(nt2 * 10 + kc) * 512 + f) = o;
  }
}

// ---------------------------------------------------------------------------
// Kernel 1: QKV projection big-tile (verbatim r9).
// ---------------------------------------------------------------------------
__global__ __launch_bounds__(256, 3) void qkv_gemm(
    const ushort* __restrict__ xb, const float* __restrict__ edge,
    const ushort* __restrict__ wt,
    ushort* __restrict__ qp, ushort* __restrict__ kS, ushort* __restrict__ vS)
{
  const int w = blockIdx.x;
  const int s = (w & 7) * 60 + (w >> 3);
  const int mg = s / 15, zh = s % 15;
  const int z = zh / 5, h = zh % 5;
  const int wave = threadIdx.x >> 6, lane = threadIdx.x & 63;
  const int m16 = lane & 15, quad = lane >> 4;
  const int m0 = mg * 256 + wave * 64;
  const ushort* atile = xb + (size_t)(m0 >> 4) * 5120 + lane * 8;
  const ushort* btile = wt + (size_t)z * 102400 + (size_t)(h * 4) * 5120 + lane * 8;

  f32x4 acc[4][4];
#pragma unroll
  for (int i = 0; i < 4; ++i)
#pragma unroll
    for (int ns = 0; ns < 4; ++ns) acc[i][ns] = (f32x4){0.f, 0.f, 0.f, 0.f};

#pragma unroll
  for (int kc = 0; kc < 10; ++kc) {
    bf16x8 af[4], bf[4];
#pragma unroll
    for (int i = 0; i < 4; ++i)
      af[i] = *reinterpret_cast<const bf16x8*>(atile + (i * 10 + kc) * 512);
#pragma unroll
    for (int ns = 0; ns < 4; ++ns)
      bf[ns] = *reinterpret_cast<const bf16x8*>(btile + (ns * 10 + kc) * 512);
    if (z == 2) {
#pragma unroll
      for (int i = 0; i < 4; ++i)
#pragma unroll
        for (int ns = 0; ns < 4; ++ns)
          acc[i][ns] = mfma32(af[i], bf[ns], acc[i][ns]);
    } else {
#pragma unroll
      for (int i = 0; i < 4; ++i)
#pragma unroll
        for (int ns = 0; ns < 4; ++ns)
          acc[i][ns] = mfma32(bf[ns], af[i], acc[i][ns]);
    }
  }

  const float QSCALE = 0.18033688011112042f;  // 0.125 * log2(e)
  const int b = m0 >> 11;
  const int bh = b * 5 + h;
  const float* eb = edge + (size_t)((b + h) & 3) * 2048;
  const int nwb = m0 & 2047;

  if (z == 0) {
#pragma unroll
    for (int i = 0; i < 4; ++i) {
      const int n = nwb + i * 16 + m16;
      const float e = eb[n] * QSCALE;
      ushort* dst = qp + ((size_t)bh * 2048 + n) * 64 + quad * 4;
#pragma unroll
      for (int ns = 0; ns < 4; ++ns) {
        ushort4 o = { f2bf(acc[i][ns][0] * e), f2bf(acc[i][ns][1] * e),
                      f2bf(acc[i][ns][2] * e), f2bf(acc[i][ns][3] * e) };
        *reinterpret_cast<ushort4*>(dst + ns * 16) = o;
      }
    }
  } else if (z == 1) {
#pragma unroll
    for (int i = 0; i < 4; ++i) {
      const int j = nwb + i * 16 + m16;
      const float e = eb[j];
      const size_t base = (size_t)bh * 131072 +
                          (size_t)((m0 >> 4) + i & 127) * 1024;
#pragma unroll
      for (int ns = 0; ns < 4; ++ns) {
        size_t a0 = base + (ns >> 1) * 512 +
                    ((((ns * 2 + (quad >> 1)) & 3) * 16 + m16)) * 8 +
                    (quad & 1) * 4;
        ushort4 o = { f2bf(acc[i][ns][0] * e), f2bf(acc[i][ns][1] * e),
                      f2bf(acc[i][ns][2] * e), f2bf(acc[i][ns][3] * e) };
        *reinterpret_cast<ushort4*>(kS + a0) = o;
      }
    }
  } else {
    const int jb = nwb >> 6;
#pragma unroll
    for (int i = 0; i < 4; ++i) {
      const int kb = i >> 1, e4 = (i & 1) * 4;
#pragma unroll
      for (int ns = 0; ns < 4; ++ns) {
        ushort4 o = { f2bf(acc[i][ns][0]), f2bf(acc[i][ns][1]),
                      f2bf(acc[i][ns][2]), f2bf(acc[i][ns][3]) };
        size_t addr = (size_t)bh * 131072 + (size_t)ns * 32768 +
                      (size_t)jb * 1024 + kb * 512 +
                      (quad * 16 + m16) * 8 + e4;
        *reinterpret_cast<ushort4*>(vS + addr) = o;
      }
    }
  }
}

// ---------------------------------------------------------------------------
// Kernel 2: attention, 64 q-rows/block at 3 waves/SIMD.
// grid 640 flat XCD-swizzled -> (bh 0..19, qt 0..31). 4 waves j-split.
// Q frags in LDS (aliased with cross-wave partials); K ping-pong prefetch
// (sched_barrier-forced); V single-buffered.
// ---------------------------------------------------------------------------
__global__ __launch_bounds__(256, 3) void attn_kernel(
    const ushort* __restrict__ qp, const ushort* __restrict__ kS,
    const ushort* __restrict__ vS, ushort* __restrict__ ao)
{
  __shared__ __align__(16) char smem[49152];   // qbuf (32KB) then lo (48KB)
  __shared__ float lrs[4][4][16];
  ushort* qbuf = (ushort*)smem;                      // [wave][qs][hf][lane*8]
  f32x4 (*lo)[16][64] = (f32x4(*)[16][64])smem;      // [3][16][64]

  const int w = blockIdx.x;
  const int s = (w & 7) * 80 + (w >> 3);
  const int bh = s >> 5, qt = s & 31;
  const int b = bh / 5, h = bh % 5;
  const int wave = threadIdx.x >> 6, lane = threadIdx.x & 63;
  const int m16 = lane & 15, quad = lane >> 4;
  const int q0 = qt * 64;
  const int laneoff = lane * 8;
  ushort* qb_w = qbuf + wave * 8 * 512;

  // stage Q A-frags into LDS (wave-private region)
#pragma unroll
  for (int qs = 0; qs < 4; ++qs) {
    const ushort* qrow = qp + ((size_t)bh * 2048 + q0 + qs * 16 + m16) * 64 + quad * 8;
    bf16x8 t0 = *reinterpret_cast<const bf16x8*>(qrow);
    bf16x8 t1 = *reinterpret_cast<const bf16x8*>(qrow + 32);
    *reinterpret_cast<bf16x8*>(qb_w + (qs * 2 + 0) * 512 + laneoff) = t0;
    *reinterpret_cast<bf16x8*>(qb_w + (qs * 2 + 1) * 512 + laneoff) = t1;
  }

  const ushort* kb_p = kS + (size_t)bh * 131072 + lane * 8;
  const ushort* vb_p = vS + (size_t)bh * 131072 + lane * 8;

  f32x4 oacc[4][4], rsacc[4];
#pragma unroll
  for (int qs = 0; qs < 4; ++qs) {
    rsacc[qs] = (f32x4){0.f, 0.f, 0.f, 0.f};
    for (int dt = 0; dt < 4; ++dt) oacc[qs][dt] = (f32x4){0.f, 0.f, 0.f, 0.f};
  }
  const bf16x8 ones8 = {(short)16256, (short)16256, (short)16256, (short)16256,
                        (short)16256, (short)16256, (short)16256, (short)16256};

  // unit u (0..15): jb = (u>>1)*4 + wave, kb = u&1
  auto load_K = [&](int u, bf16x8 kf[2][2]) {
    const int jb = (u >> 1) * 4 + wave, kb = u & 1;
#pragma unroll
    for (int ss = 0; ss < 2; ++ss)
#pragma unroll
      for (int hf = 0; hf < 2; ++hf)
        kf[ss][hf] = *reinterpret_cast<const bf16x8*>(
            kb_p + (size_t)(jb * 4 + kb * 2 + ss) * 1024 + hf * 512);
  };
  auto load_V = [&](int u, bf16x8 vf[4]) {
    const int jb = (u >> 1) * 4 + wave, kb = u & 1;
#pragma unroll
    for (int dt = 0; dt < 4; ++dt)
      vf[dt] = *reinterpret_cast<const bf16x8*>(
          vb_p + (size_t)dt * 32768 + (size_t)jb * 1024 + kb * 512);
  };
  auto compute_unit = [&](bf16x8 kf[2][2], bf16x8 vf[4]) {
#pragma unroll
    for (int qs = 0; qs < 4; ++qs) {
      bf16x8 qf0 = *reinterpret_cast<const bf16x8*>(qb_w + (qs * 2 + 0) * 512 + laneoff);
      bf16x8 qf1 = *reinterpret_cast<const bf16x8*>(qb_w + (qs * 2 + 1) * 512 + laneoff);
      f32x4 st0 = (f32x4){0.f, 0.f, 0.f, 0.f};
      f32x4 st1 = (f32x4){0.f, 0.f, 0.f, 0.f};
      st0 = mfma32(kf[0][0], qf0, st0);
      st0 = mfma32(kf[0][1], qf1, st0);
      st1 = mfma32(kf[1][0], qf0, st1);
      st1 = mfma32(kf[1][1], qf1, st1);
      unsigned b0 = __float_as_uint(fexp2(st0[0]));
      unsigned b1 = __float_as_uint(fexp2(st0[1]));
      unsigned b2 = __float_as_uint(fexp2(st0[2]));
      unsigned b3 = __float_as_uint(fexp2(st0[3]));
      unsigned b4 = __float_as_uint(fexp2(st1[0]));
      unsigned b5 = __float_as_uint(fexp2(st1[1]));
      unsigned b6 = __float_as_uint(fexp2(st1[2]));
      unsigned b7 = __float_as_uint(fexp2(st1[3]));
      union { unsigned u[4]; bf16x8 v; } pk;
      pk.u[0] = __builtin_amdgcn_perm(b1, b0, 0x07060302u);
      pk.u[1] = __builtin_amdgcn_perm(b3, b2, 0x07060302u);
      pk.u[2] = __builtin_amdgcn_perm(b5, b4, 0x07060302u);
      pk.u[3] = __builtin_amdgcn_perm(b7, b6, 0x07060302u);
      rsacc[qs] = mfma32(ones8, pk.v, rsacc[qs]);
#pragma unroll
      for (int dt = 0; dt < 4; ++dt)
        oacc[qs][dt] = mfma32(vf[dt], pk.v, oacc[qs][dt]);
    }
  };

  bf16x8 kA[2][2], kB[2][2], vC[4];
  load_K(0, kA);
  __builtin_amdgcn_sched_barrier(0);
#pragma unroll
  for (int u = 0; u < 16; ++u) {
    load_V(u, vC);
    if (u + 1 < 16) {
      if (u & 1) load_K(u + 1, kA); else load_K(u + 1, kB);
    }
    __builtin_amdgcn_sched_barrier(0);   // prefetch loads must issue here
    if (u & 1) compute_unit(kB, vC); else compute_unit(kA, vC);
    __builtin_amdgcn_sched_barrier(0);
  }

  // LDS region switches from qbuf to lo — all qbuf reads must be done
  __syncthreads();

  if (wave > 0) {
#pragma unroll
    for (int qs = 0; qs < 4; ++qs)
#pragma unroll
      for (int dt = 0; dt < 4; ++dt)
        lo[wave - 1][qs * 4 + dt][lane] = oacc[qs][dt];
  }
  if (quad == 0) {
#pragma unroll
    for (int qs = 0; qs < 4; ++qs)
      lrs[wave][qs][m16] = rsacc[qs][0];  // all regs identical (ones-A)
  }
  __syncthreads();
  if (wave == 0) {
#pragma unroll
    for (int qs = 0; qs < 4; ++qs) {
      float inv = 1.0f / (lrs[0][qs][m16] + lrs[1][qs][m16] +
                          lrs[2][qs][m16] + lrs[3][qs][m16]);
      const int mt2 = b * 128 + qt * 4 + qs;  // ao tile row
#pragma unroll
      for (int dt = 0; dt < 4; ++dt) {
        f32x4 a = oacc[qs][dt];
        a += lo[0][qs * 4 + dt][lane];
        a += lo[1][qs * 4 + dt][lane];
        a += lo[2][qs * 4 + dt][lane];
        unsigned r0 = f2bf(a[0] * inv), r1 = f2bf(a[1] * inv);
        unsigned r2 = f2bf(a[2] * inv), r3 = f2bf(a[3] * inv);
        uint2 ww;
        ww.x = r0 | (r1 << 16);
        ww.y = r2 | (r3 << 16);
        size_t addr = (size_t)(mt2 * 10 + h * 2 + (dt >> 1)) * 512 +
                      ((((dt & 1) * 2 + (quad >> 1)) * 16 + m16)) * 8 +
                      (quad & 1) * 4;
        *reinterpret_cast<uint2*>(ao + addr) = ww;
      }
    }
  }
}

// ---------------------------------------------------------------------------
// Kernel 3: output projection big-tile, swapped operands (verbatim r9).
// ---------------------------------------------------------------------------
__global__ __launch_bounds__(128, 4) void oproj_gemm(
    const ushort* __restrict__ ao, const ushort* __restrict__ wt,
    const float* __restrict__ bo, float* __restrict__ out)
{
  const int w = blockIdx.x;
  const int s = (w & 7) * 40 + (w >> 3);
  const int mg = s / 5, ct = s % 5;
  const int wave = threadIdx.x >> 6, lane = threadIdx.x & 63;
  const int m16 = lane & 15, quad = lane >> 4;
  const int m0 = mg * 128 + wave * 64;
  const int n0 = ct * 64;
  const ushort* atile = ao + (size_t)(m0 >> 4) * 5120 + lane * 8;
  const ushort* btile = wt + (size_t)3 * 102400 + (size_t)(ct * 4) * 5120 + lane * 8;

  f32x4 acc[4][4];
#pragma unroll
  for (int i = 0; i < 4; ++i)
#pragma unroll
    for (int ns = 0; ns < 4; ++ns) acc[i][ns] = (f32x4){0.f, 0.f, 0.f, 0.f};

#pragma unroll
  for (int kc = 0; kc < 10; ++kc) {
    bf16x8 af[4], bf[4];
#pragma unroll
    for (int i = 0; i < 4; ++i)
      af[i] = *reinterpret_cast<const bf16x8*>(atile + (i * 10 + kc) * 512);
#pragma unroll
    for (int ns = 0; ns < 4; ++ns)
      bf[ns] = *reinterpret_cast<const bf16x8*>(btile + (ns * 10 + kc) * 512);
#pragma unroll
    for (int i = 0; i < 4; ++i)
#pragma unroll
      for (int ns = 0; ns < 4; ++ns)
        acc[i][ns] = mfma32(bf[ns], af[i], acc[i][ns]);
  }

  float4 bb[4];
#pragma unroll
  for (int ns = 0; ns < 4; ++ns)
    bb[ns] = *reinterpret_cast<const float4*>(bo + n0 + ns * 16 + quad * 4);
#pragma unroll
  for (int i = 0; i < 4; ++i) {
    const int mrow = m0 + i * 16 + m16;
#pragma unroll
    for (int ns = 0; ns < 4; ++ns) {
      float4 o;
      o.x = acc[i][ns][0] + bb[ns].x;
      o.y = acc[i][ns][1] + bb[ns].y;
      o.z = acc[i][ns][2] + bb[ns].z;
      o.w = acc[i][ns][3] + bb[ns].w;
      *reinterpret_cast<float4*>(
          out + (size_t)mrow * 320 + n0 + ns * 16 + quad * 4) = o;
    }
  }
}

// ---------------------------------------------------------------------------
extern "C" void kernel_launch(void* const* d_in, const int* in_sizes, int n_in,
                              void* d_out, int out_size, void* d_ws, size_t ws_size,
                              hipStream_t stream) {
  const float* x    = (const float*)d_in[0];
  const float* edge = (const float*)d_in[1];
  const float* Wq   = (const float*)d_in[2];
  const float* Wk   = (const float*)d_in[3];
  const float* Wv   = (const float*)d_in[4];
  const float* Wo   = (const float*)d_in[5];
  const float* bo   = (const float*)d_in[6];
  float* out = (float*)d_out;

  ushort* xb = (ushort*)d_ws;                       // 8192*320
  ushort* wt = xb + (size_t)8192 * 320;             // 4*320*320
  ushort* qp = wt + (size_t)4 * 320 * 320;          // 20*2048*64
  ushort* kS = qp + (size_t)20 * 2048 * 64;
  ushort* vS = kS + (size_t)20 * 2048 * 64;
  ushort* ao = vS + (size_t)20 * 2048 * 64;

  prep_kernel<<<3360, 256, 0, stream>>>(x, Wq, Wk, Wv, Wo, xb, wt);
  qkv_gemm<<<480, 256, 0, stream>>>(xb, edge, wt, qp, kS, vS);
  attn_kernel<<<640, 256, 0, stream>>>(qp, kS, vS, ao);
  oproj_gemm<<<320, 128, 0, stream>>>(ao, wt, bo, out);
}

// Round 11
// 124.074 us; speedup vs baseline: 1.0664x; 1.0664x over previous
//
#include <hip/hip_runtime.h>
#include <hip/hip_bf16.h>
#include <math.h>

// B=4, N=2048, C=320, H=5, D=64, INNER=320, BH=20
// logit = (q*0.125*log2e*e_i) . (k*e_j); softmax via exp2 (bounded, no max).
// e_bh = edge[(b+h)%4]  (batch-minor edge tiling vs batch-major heads)
//
// Fragment-major layouts (every main-loop load = lane-contiguous b128):
//  xb  tiles (mt2=m/16, kc=k/32): elem (qq*16+mm)*8+e  = x[m][k], qq=(k%32)>>3
//  wt  tiles (z, nt2=n/16, kc):   elem (qq*16+nn)*8+e  = W[k][n]
//  kS  [bh][j/16][d/32][slot]:    slot ((d>>3)&3)*16+(j&15), e=d&7
//  vS  [bh][d/16][j/64][kb][slot]: PV mfma32 A-frag order (see r3 notes)
//  ao  tiles like xb (A-operand of oproj)
//  qp  row-major [bh][n][64]
//
// NOTE (r11): attention is transcendental-bound — 8.4e8 v_exp_f32 at
// quarter rate ≈ 42 µs chip-wide floor. Memory-side changes are neutral
// (measured r4..r10). attn kept in its best (r9) form.

typedef short bf16x8 __attribute__((ext_vector_type(8)));
typedef float f32x4 __attribute__((ext_vector_type(4)));

static __device__ __forceinline__ ushort f2bf(float f) {
  union { float f; unsigned u; } v; v.f = f;
  unsigned r = (v.u + 0x7fffu + ((v.u >> 16) & 1u)) >> 16;
  return (ushort)r;
}
static __device__ __forceinline__ float fexp2(float x) {
#if __has_builtin(__builtin_amdgcn_exp2f)
  return __builtin_amdgcn_exp2f(x);
#else
  return exp2f(x);
#endif
}
static __device__ __forceinline__ f32x4 mfma32(bf16x8 a, bf16x8 b, f32x4 c) {
  return __builtin_amdgcn_mfma_f32_16x16x32_bf16(a, b, c, 0, 0, 0);
}

// ---------------------------------------------------------------------------
// Prep (fused): flat grid 3360. (verbatim r9)
// ---------------------------------------------------------------------------
__global__ __launch_bounds__(256) void prep_kernel(
    const float* __restrict__ x,
    const float* __restrict__ Wq, const float* __restrict__ Wk,
    const float* __restrict__ Wv, const float* __restrict__ Wo,
    ushort* __restrict__ xb, ushort* __restrict__ wt)
{
  const int w = blockIdx.x;
  if (w < 2560) {
    const int t = threadIdx.x;
    const int mt2 = w / 5;
    const int kc = (w % 5) * 2 + (t >> 7);
    const int f = (t & 127) * 4;
    const int qq = f >> 7, mm = (f >> 3) & 15, e0 = f & 7;
    float4 v = *reinterpret_cast<const float4*>(
        x + (size_t)(mt2 * 16 + mm) * 320 + kc * 32 + qq * 8 + e0);
    ushort4 o = { f2bf(v.x), f2bf(v.y), f2bf(v.z), f2bf(v.w) };
    *reinterpret_cast<ushort4*>(xb + (size_t)(mt2 * 10 + kc) * 512 + f) = o;
  } else {
    const int w2 = w - 2560;
    const int nt2 = w2 % 20, kc = (w2 / 20) % 10, z = w2 / 200;
    const float* W = z == 0 ? Wq : z == 1 ? Wk : z == 2 ? Wv : Wo;
    const int f = threadIdx.x * 2;
    const int qq = f >> 7, nn = (f >> 3) & 15, e0 = f & 7;
    const int k = kc * 32 + qq * 8 + e0, n = nt2 * 16 + nn;
    float v0 = W[(size_t)k * 320 + n];
    float v1 = W[(size_t)(k + 1) * 320 + n];
    ushort2 o = { f2bf(v0), f2bf(v1) };
    *reinterpret_cast<ushort2*>(
        wt + (size_t)z * 102400 + (size_t)(nt2 * 10 + kc) * 512 + f) = o;
  }
}

// ---------------------------------------------------------------------------
// Kernel 1: QKV projection big-tile (verbatim r9).
// ---------------------------------------------------------------------------
__global__ __launch_bounds__(256, 3) void qkv_gemm(
    const ushort* __restrict__ xb, const float* __restrict__ edge,
    const ushort* __restrict__ wt,
    ushort* __restrict__ qp, ushort* __restrict__ kS, ushort* __restrict__ vS)
{
  const int w = blockIdx.x;
  const int s = (w & 7) * 60 + (w >> 3);
  const int mg = s / 15, zh = s % 15;
  const int z = zh / 5, h = zh % 5;
  const int wave = threadIdx.x >> 6, lane = threadIdx.x & 63;
  const int m16 = lane & 15, quad = lane >> 4;
  const int m0 = mg * 256 + wave * 64;
  const ushort* atile = xb + (size_t)(m0 >> 4) * 5120 + lane * 8;
  const ushort* btile = wt + (size_t)z * 102400 + (size_t)(h * 4) * 5120 + lane * 8;

  f32x4 acc[4][4];
#pragma unroll
  for (int i = 0; i < 4; ++i)
#pragma unroll
    for (int ns = 0; ns < 4; ++ns) acc[i][ns] = (f32x4){0.f, 0.f, 0.f, 0.f};

#pragma unroll
  for (int kc = 0; kc < 10; ++kc) {
    bf16x8 af[4], bf[4];
#pragma unroll
    for (int i = 0; i < 4; ++i)
      af[i] = *reinterpret_cast<const bf16x8*>(atile + (i * 10 + kc) * 512);
#pragma unroll
    for (int ns = 0; ns < 4; ++ns)
      bf[ns] = *reinterpret_cast<const bf16x8*>(btile + (ns * 10 + kc) * 512);
    if (z == 2) {
#pragma unroll
      for (int i = 0; i < 4; ++i)
#pragma unroll
        for (int ns = 0; ns < 4; ++ns)
          acc[i][ns] = mfma32(af[i], bf[ns], acc[i][ns]);
    } else {
#pragma unroll
      for (int i = 0; i < 4; ++i)
#pragma unroll
        for (int ns = 0; ns < 4; ++ns)
          acc[i][ns] = mfma32(bf[ns], af[i], acc[i][ns]);
    }
  }

  const float QSCALE = 0.18033688011112042f;  // 0.125 * log2(e)
  const int b = m0 >> 11;
  const int bh = b * 5 + h;
  const float* eb = edge + (size_t)((b + h) & 3) * 2048;
  const int nwb = m0 & 2047;

  if (z == 0) {
#pragma unroll
    for (int i = 0; i < 4; ++i) {
      const int n = nwb + i * 16 + m16;
      const float e = eb[n] * QSCALE;
      ushort* dst = qp + ((size_t)bh * 2048 + n) * 64 + quad * 4;
#pragma unroll
      for (int ns = 0; ns < 4; ++ns) {
        ushort4 o = { f2bf(acc[i][ns][0] * e), f2bf(acc[i][ns][1] * e),
                      f2bf(acc[i][ns][2] * e), f2bf(acc[i][ns][3] * e) };
        *reinterpret_cast<ushort4*>(dst + ns * 16) = o;
      }
    }
  } else if (z == 1) {
#pragma unroll
    for (int i = 0; i < 4; ++i) {
      const int j = nwb + i * 16 + m16;
      const float e = eb[j];
      const size_t base = (size_t)bh * 131072 +
                          (size_t)((m0 >> 4) + i & 127) * 1024;
#pragma unroll
      for (int ns = 0; ns < 4; ++ns) {
        size_t a0 = base + (ns >> 1) * 512 +
                    ((((ns * 2 + (quad >> 1)) & 3) * 16 + m16)) * 8 +
                    (quad & 1) * 4;
        ushort4 o = { f2bf(acc[i][ns][0] * e), f2bf(acc[i][ns][1] * e),
                      f2bf(acc[i][ns][2] * e), f2bf(acc[i][ns][3] * e) };
        *reinterpret_cast<ushort4*>(kS + a0) = o;
      }
    }
  } else {
    const int jb = nwb >> 6;
#pragma unroll
    for (int i = 0; i < 4; ++i) {
      const int kb = i >> 1, e4 = (i & 1) * 4;
#pragma unroll
      for (int ns = 0; ns < 4; ++ns) {
        ushort4 o = { f2bf(acc[i][ns][0]), f2bf(acc[i][ns][1]),
                      f2bf(acc[i][ns][2]), f2bf(acc[i][ns][3]) };
        size_t addr = (size_t)bh * 131072 + (size_t)ns * 32768 +
                      (size_t)jb * 1024 + kb * 512 +
                      (quad * 16 + m16) * 8 + e4;
        *reinterpret_cast<ushort4*>(vS + addr) = o;
      }
    }
  }
}

// ---------------------------------------------------------------------------
// Kernel 2: attention (verbatim r9 — best measured). 32q blocks, grid 1280
// flat XCD-swizzled; 4 waves j-split; register Q; K/V ping-pong prefetch
// forced with sched_barrier(0); 3 waves/SIMD.
// ---------------------------------------------------------------------------
__global__ __launch_bounds__(256, 3) void attn_kernel(
    const ushort* __restrict__ qp, const ushort* __restrict__ kS,
    const ushort* __restrict__ vS, ushort* __restrict__ ao)
{
  __shared__ f32x4 lo[3][8][64];   // 24 KB cross-wave partials
  __shared__ float lrs[4][2][16];
  const int w = blockIdx.x;
  const int s = (w & 7) * 160 + (w >> 3);
  const int bh = s >> 6, qt = s & 63;
  const int b = bh / 5, h = bh % 5;
  const int wave = threadIdx.x >> 6, lane = threadIdx.x & 63;
  const int m16 = lane & 15, quad = lane >> 4;
  const int q0 = qt * 32;

  bf16x8 qf[2][2];
#pragma unroll
  for (int qs = 0; qs < 2; ++qs) {
    const ushort* qrow = qp + ((size_t)bh * 2048 + q0 + qs * 16 + m16) * 64;
    qf[qs][0] = *reinterpret_cast<const bf16x8*>(qrow + quad * 8);
    qf[qs][1] = *reinterpret_cast<const bf16x8*>(qrow + 32 + quad * 8);
  }
  const ushort* kb_p = kS + (size_t)bh * 131072 + lane * 8;
  const ushort* vb_p = vS + (size_t)bh * 131072 + lane * 8;

  f32x4 oacc[2][4], rsacc[2];
#pragma unroll
  for (int qs = 0; qs < 2; ++qs) {
    rsacc[qs] = (f32x4){0.f, 0.f, 0.f, 0.f};
    for (int dt = 0; dt < 4; ++dt) oacc[qs][dt] = (f32x4){0.f, 0.f, 0.f, 0.f};
  }
  const bf16x8 ones8 = {(short)16256, (short)16256, (short)16256, (short)16256,
                        (short)16256, (short)16256, (short)16256, (short)16256};

  auto load_unit = [&](int u, bf16x8 kf[2][2], bf16x8 vf[4]) {
    const int jb = (u >> 1) * 4 + wave, kb = u & 1;
#pragma unroll
    for (int ss = 0; ss < 2; ++ss)
#pragma unroll
      for (int hf = 0; hf < 2; ++hf)
        kf[ss][hf] = *reinterpret_cast<const bf16x8*>(
            kb_p + (size_t)(jb * 4 + kb * 2 + ss) * 1024 + hf * 512);
#pragma unroll
    for (int dt = 0; dt < 4; ++dt)
      vf[dt] = *reinterpret_cast<const bf16x8*>(
          vb_p + (size_t)dt * 32768 + (size_t)jb * 1024 + kb * 512);
  };
  auto compute_unit = [&](bf16x8 kf[2][2], bf16x8 vf[4]) {
#pragma unroll
    for (int qs = 0; qs < 2; ++qs) {
      f32x4 st0 = (f32x4){0.f, 0.f, 0.f, 0.f};
      f32x4 st1 = (f32x4){0.f, 0.f, 0.f, 0.f};
      st0 = mfma32(kf[0][0], qf[qs][0], st0);
      st0 = mfma32(kf[0][1], qf[qs][1], st0);
      st1 = mfma32(kf[1][0], qf[qs][0], st1);
      st1 = mfma32(kf[1][1], qf[qs][1], st1);
      unsigned b0 = __float_as_uint(fexp2(st0[0]));
      unsigned b1 = __float_as_uint(fexp2(st0[1]));
      unsigned b2 = __float_as_uint(fexp2(st0[2]));
      unsigned b3 = __float_as_uint(fexp2(st0[3]));
      unsigned b4 = __float_as_uint(fexp2(st1[0]));
      unsigned b5 = __float_as_uint(fexp2(st1[1]));
      unsigned b6 = __float_as_uint(fexp2(st1[2]));
      unsigned b7 = __float_as_uint(fexp2(st1[3]));
      union { unsigned u[4]; bf16x8 v; } pk;
      pk.u[0] = __builtin_amdgcn_perm(b1, b0, 0x07060302u);
      pk.u[1] = __builtin_amdgcn_perm(b3, b2, 0x07060302u);
      pk.u[2] = __builtin_amdgcn_perm(b5, b4, 0x07060302u);
      pk.u[3] = __builtin_amdgcn_perm(b7, b6, 0x07060302u);
      rsacc[qs] = mfma32(ones8, pk.v, rsacc[qs]);
#pragma unroll
      for (int dt = 0; dt < 4; ++dt)
        oacc[qs][dt] = mfma32(vf[dt], pk.v, oacc[qs][dt]);
    }
  };

  bf16x8 kA[2][2], vA[4], kB[2][2], vB[4];
  load_unit(0, kA, vA);
  __builtin_amdgcn_sched_barrier(0);
#pragma unroll
  for (int u = 0; u < 16; u += 2) {
    load_unit(u + 1, kB, vB);
    __builtin_amdgcn_sched_barrier(0);
    compute_unit(kA, vA);
    if (u + 2 < 16) load_unit(u + 2, kA, vA);
    __builtin_amdgcn_sched_barrier(0);
    compute_unit(kB, vB);
    __builtin_amdgcn_sched_barrier(0);
  }

  if (wave > 0) {
#pragma unroll
    for (int qs = 0; qs < 2; ++qs)
#pragma unroll
      for (int dt = 0; dt < 4; ++dt)
        lo[wave - 1][qs * 4 + dt][lane] = oacc[qs][dt];
  }
  if (quad == 0) {
    lrs[wave][0][m16] = rsacc[0][0];
    lrs[wave][1][m16] = rsacc[1][0];
  }
  __syncthreads();
  if (wave == 0) {
#pragma unroll
    for (int qs = 0; qs < 2; ++qs) {
      float inv = 1.0f / (lrs[0][qs][m16] + lrs[1][qs][m16] +
                          lrs[2][qs][m16] + lrs[3][qs][m16]);
      const int mt2 = b * 128 + qt * 2 + qs;
#pragma unroll
      for (int dt = 0; dt < 4; ++dt) {
        f32x4 a = oacc[qs][dt];
        a += lo[0][qs * 4 + dt][lane];
        a += lo[1][qs * 4 + dt][lane];
        a += lo[2][qs * 4 + dt][lane];
        unsigned r0 = f2bf(a[0] * inv), r1 = f2bf(a[1] * inv);
        unsigned r2 = f2bf(a[2] * inv), r3 = f2bf(a[3] * inv);
        uint2 ww;
        ww.x = r0 | (r1 << 16);
        ww.y = r2 | (r3 << 16);
        size_t addr = (size_t)(mt2 * 10 + h * 2 + (dt >> 1)) * 512 +
                      ((((dt & 1) * 2 + (quad >> 1)) * 16 + m16)) * 8 +
                      (quad & 1) * 4;
        *reinterpret_cast<uint2*>(ao + addr) = ww;
      }
    }
  }
}

// ---------------------------------------------------------------------------
// Kernel 3: output projection, swapped operands; r11: 4-wave blocks with
// wave = 32m x 64n -> 1280 waves (full SIMD coverage vs 640 before).
// grid 320 flat XCD-swizzled -> (mg 0..63, ct 0..4); block covers 128m.
// ---------------------------------------------------------------------------
__global__ __launch_bounds__(256, 3) void oproj_gemm(
    const ushort* __restrict__ ao, const ushort* __restrict__ wt,
    const float* __restrict__ bo, float* __restrict__ out)
{
  const int w = blockIdx.x;
  const int s = (w & 7) * 40 + (w >> 3);
  const int mg = s / 5, ct = s % 5;
  const int wave = threadIdx.x >> 6, lane = threadIdx.x & 63;
  const int m16 = lane & 15, quad = lane >> 4;
  const int m0 = mg * 128 + wave * 32;
  const int n0 = ct * 64;
  const ushort* atile = ao + (size_t)(m0 >> 4) * 5120 + lane * 8;
  const ushort* btile = wt + (size_t)3 * 102400 + (size_t)(ct * 4) * 5120 + lane * 8;

  f32x4 acc[2][4];
#pragma unroll
  for (int i = 0; i < 2; ++i)
#pragma unroll
    for (int ns = 0; ns < 4; ++ns) acc[i][ns] = (f32x4){0.f, 0.f, 0.f, 0.f};

#pragma unroll
  for (int kc = 0; kc < 10; ++kc) {
    bf16x8 af[2], bf[4];
#pragma unroll
    for (int i = 0; i < 2; ++i)
      af[i] = *reinterpret_cast<const bf16x8*>(atile + (i * 10 + kc) * 512);
#pragma unroll
    for (int ns = 0; ns < 4; ++ns)
      bf[ns] = *reinterpret_cast<const bf16x8*>(btile + (ns * 10 + kc) * 512);
    // swapped: lane holds out-row = m16 within i-tile, 4 consecutive cols
#pragma unroll
    for (int i = 0; i < 2; ++i)
#pragma unroll
      for (int ns = 0; ns < 4; ++ns)
        acc[i][ns] = mfma32(bf[ns], af[i], acc[i][ns]);
  }

  float4 bb[4];
#pragma unroll
  for (int ns = 0; ns < 4; ++ns)
    bb[ns] = *reinterpret_cast<const float4*>(bo + n0 + ns * 16 + quad * 4);
#pragma unroll
  for (int i = 0; i < 2; ++i) {
    const int mrow = m0 + i * 16 + m16;
#pragma unroll
    for (int ns = 0; ns < 4; ++ns) {
      float4 o;
      o.x = acc[i][ns][0] + bb[ns].x;
      o.y = acc[i][ns][1] + bb[ns].y;
      o.z = acc[i][ns][2] + bb[ns].z;
      o.w = acc[i][ns][3] + bb[ns].w;
      *reinterpret_cast<float4*>(
          out + (size_t)mrow * 320 + n0 + ns * 16 + quad * 4) = o;
    }
  }
}

// ---------------------------------------------------------------------------
extern "C" void kernel_launch(void* const* d_in, const int* in_sizes, int n_in,
                              void* d_out, int out_size, void* d_ws, size_t ws_size,
                              hipStream_t stream) {
  const float* x    = (const float*)d_in[0];
  const float* edge = (const float*)d_in[1];
  const float* Wq   = (const float*)d_in[2];
  const float* Wk   = (const float*)d_in[3];
  const float* Wv   = (const float*)d_in[4];
  const float* Wo   = (const float*)d_in[5];
  const float* bo   = (const float*)d_in[6];
  float* out = (float*)d_out;

  ushort* xb = (ushort*)d_ws;                       // 8192*320
  ushort* wt = xb + (size_t)8192 * 320;             // 4*320*320
  ushort* qp = wt + (size_t)4 * 320 * 320;          // 20*2048*64
  ushort* kS = qp + (size_t)20 * 2048 * 64;
  ushort* vS = kS + (size_t)20 * 2048 * 64;
  ushort* ao = vS + (size_t)20 * 2048 * 64;

  prep_kernel<<<3360, 256, 0, stream>>>(x, Wq, Wk, Wv, Wo, xb, wt);
  qkv_gemm<<<480, 256, 0, stream>>>(xb, edge, wt, qp, kS, vS);
  attn_kernel<<<1280, 256, 0, stream>>>(qp, kS, vS, ao);
  oproj_gemm<<<320, 256, 0, stream>>>(ao, wt, bo, out);
}